// Round 6
// baseline (231.175 us; speedup 1.0000x reference)
//
#include <hip/hip_runtime.h>
#include <stdint.h>

typedef float  f32x4 __attribute__((ext_vector_type(4)));
typedef short  s16x8 __attribute__((ext_vector_type(8)));

constexpr int Kdim    = 1024;
constexpr int Cdim    = 16;
constexpr int NCHUNK  = 8;                 // grid = 512 -> 2 blocks/CU (LDS 74.2KB x2 <= 160KB)
constexpr int ROWS_CH = 128;               // rows per block
constexpr int TROWS   = 32;                // rows per LDS tile
constexpr int NTILE   = ROWS_CH / TROWS;   // 4
constexpr int RS      = Kdim + 8;          // bf16 row stride (2064B = 129*16B: aligned, rotates banks)

static __device__ __forceinline__ ushort f2bf(float f) {
  uint32_t u = __builtin_bit_cast(uint32_t, f);
  u += 0x7FFFu + ((u >> 16) & 1u);         // RNE
  return (ushort)(u >> 16);
}

// LDS-only barrier: ds ops drained, global prefetches stay IN FLIGHT across it.
static __device__ __forceinline__ void bar_lds() {
  __builtin_amdgcn_sched_barrier(0);
  asm volatile("s_waitcnt lgkmcnt(0)" ::: "memory");
  __builtin_amdgcn_s_barrier();
  __builtin_amdgcn_sched_barrier(0);
}

// Single fused kernel.
// Phase 1 (verified round-5 structure): one read of x; r-partials in REGISTERS; col via MFMA -> col_ws[b][c][i].
// Per-batch sync: 8 chunk-blocks of b are consecutive blockIdx -> complete groups always co-resident -> no deadlock.
// Phase 2: dot racc vs complete col (L3-hot), deterministic partials in sparts; last block per b broadcasts out.
__global__ __launch_bounds__(256, 2) void k_fused(const float* __restrict__ x, const float* __restrict__ Wr,
                                                  const float* __restrict__ Wc, const float* __restrict__ b_row,
                                                  const float* __restrict__ b_col, float* __restrict__ col_ws,
                                                  float* __restrict__ sparts, int* __restrict__ cntA,
                                                  int* __restrict__ cntB, float* __restrict__ out) {
  __shared__ ushort x_l[TROWS * RS];        // 66,048 B bf16 tile
  __shared__ float  colp[2][4 * 64 * 4];    //  8,192 B MFMA partials (double-buffered)
  __shared__ float  wred[4 * Cdim];
  __shared__ int    lastFlag;

  const int t    = threadIdx.x;
  const int lane = t & 63;
  const int w    = t >> 6;
  const int b    = blockIdx.x >> 3;
  const int ch   = blockIdx.x & 7;
  const int i0   = ch * ROWS_CH;
  const float* xb = x + (size_t)b * Kdim * Kdim;
  const float* xt = xb + 4 * t;

  // ---- start the x prefetch ring FIRST (HBM latency long); depth-8: 128B/thread in flight
  f32x4 pa0, pa1, pa2, pa3, pb0, pb1, pb2, pb3;
  pa0 = *(const f32x4*)(xt + (size_t)(i0 + 0) * Kdim);
  pa1 = *(const f32x4*)(xt + (size_t)(i0 + 1) * Kdim);
  pa2 = *(const f32x4*)(xt + (size_t)(i0 + 2) * Kdim);
  pa3 = *(const f32x4*)(xt + (size_t)(i0 + 3) * Kdim);

  // ---- hoist B operand: wave w covers K-half (w>>1); build bf16 fragments from fp32 Wc (L2-hot)
  const int kh = w >> 1;
  const int kg = lane >> 4;
  const float* wcrow = Wc + (size_t)(lane & 15) * Kdim;
  s16x8 wfrag[16];
  #pragma unroll
  for (int s = 0; s < 16; ++s) {
    const float* p = wcrow + (kh * 16 + s) * 32 + kg * 8;
    f32x4 lo = *(const f32x4*)p;
    f32x4 hi = *(const f32x4*)(p + 4);
    s16x8 f;
    f[0] = (short)f2bf(lo.x); f[1] = (short)f2bf(lo.y); f[2] = (short)f2bf(lo.z); f[3] = (short)f2bf(lo.w);
    f[4] = (short)f2bf(hi.x); f[5] = (short)f2bf(hi.y); f[6] = (short)f2bf(hi.z); f[7] = (short)f2bf(hi.w);
    wfrag[s] = f;
  }

  float racc[Cdim][4];
  #pragma unroll
  for (int c = 0; c < Cdim; ++c) { racc[c][0] = racc[c][1] = racc[c][2] = racc[c][3] = 0.f; }

  auto proc_row = [&](int row, int grow, f32x4 v) {
    const float* wrp = Wr + grow;            // Wr[c][grow]: uniform -> s_load, scalar-cache resident
    #pragma unroll
    for (int c = 0; c < Cdim; ++c) {
      const float wv = wrp[(size_t)c * Kdim];
      racc[c][0] = fmaf(wv, v.x, racc[c][0]);
      racc[c][1] = fmaf(wv, v.y, racc[c][1]);
      racc[c][2] = fmaf(wv, v.z, racc[c][2]);
      racc[c][3] = fmaf(wv, v.w, racc[c][3]);
    }
    ushort4 u4 = make_ushort4(f2bf(v.x), f2bf(v.y), f2bf(v.z), f2bf(v.w));
    *(ushort4*)&x_l[row * RS + 4 * t] = u4;
  };

  auto phase_c = [&](int p, int r0p) {      // combine K-halves, store col in [b][c][i] (contig in i)
    if (t < 128) {
      const int it = t >> 6;
      const int l  = t & 63;
      f32x4 va = *(const f32x4*)&colp[p][(it * 64 + l) * 4];
      f32x4 vb = *(const f32x4*)&colp[p][((it + 2) * 64 + l) * 4];
      const int c     = l & 15;
      const int rbase = r0p + it * 16 + ((l >> 4) << 2);   // D row = (lane>>4)*4 + q
      f32x4 o = va + vb;
      *(f32x4*)(col_ws + ((size_t)(b * Cdim + c)) * Kdim + rbase) = o;
    }
  };

  for (int tl = 0; tl < NTILE; ++tl) {
    const int r0 = i0 + tl * TROWS;

    if (tl) phase_c((tl - 1) & 1, r0 - TROWS);   // prev tile's col store overlaps phase A

    // ---- phase A: stream 32 rows; pa/pb alternate; last prefetch targets next tile (survives barriers)
    for (int g = 0; g < 8; g += 2) {
      const int nr1 = r0 + (g + 1) * 4;
      pb0 = *(const f32x4*)(xt + (size_t)(nr1 + 0) * Kdim);
      pb1 = *(const f32x4*)(xt + (size_t)(nr1 + 1) * Kdim);
      pb2 = *(const f32x4*)(xt + (size_t)(nr1 + 2) * Kdim);
      pb3 = *(const f32x4*)(xt + (size_t)(nr1 + 3) * Kdim);
      proc_row(g * 4 + 0, r0 + g * 4 + 0, pa0);
      proc_row(g * 4 + 1, r0 + g * 4 + 1, pa1);
      proc_row(g * 4 + 2, r0 + g * 4 + 2, pa2);
      proc_row(g * 4 + 3, r0 + g * 4 + 3, pa3);
      const int nr2 = r0 + (g + 2) * 4;          // == r0+32 when g==6 -> next tile group 0
      if (g + 2 < 8 || tl + 1 < NTILE) {         // guards OOB read past chunk end
        pa0 = *(const f32x4*)(xt + (size_t)(nr2 + 0) * Kdim);
        pa1 = *(const f32x4*)(xt + (size_t)(nr2 + 1) * Kdim);
        pa2 = *(const f32x4*)(xt + (size_t)(nr2 + 2) * Kdim);
        pa3 = *(const f32x4*)(xt + (size_t)(nr2 + 3) * Kdim);
      }
      proc_row(g * 4 + 4, nr1 + 0, pb0);
      proc_row(g * 4 + 5, nr1 + 1, pb1);
      proc_row(g * 4 + 6, nr1 + 2, pb2);
      proc_row(g * 4 + 7, nr1 + 3, pb3);
    }
    bar_lds();                                   // x_l visible; global ring stays in flight

    // ---- phase B: col-direction MFMA. wave w: i-tile (w&1), K-half (w>>1). B operand from regs.
    {
      const int it   = w & 1;
      const int arow = it * 16 + (lane & 15);
      f32x4 acc = {0.f, 0.f, 0.f, 0.f};
      #pragma unroll
      for (int s = 0; s < 16; ++s) {
        const int ks = kh * 16 + s;
        s16x8 a = *(const s16x8*)&x_l[arow * RS + ks * 32 + kg * 8];
        acc = __builtin_amdgcn_mfma_f32_16x16x32_bf16(a, wfrag[s], acc, 0, 0, 0);
      }
      *(f32x4*)&colp[tl & 1][(w * 64 + lane) * 4] = acc;
    }
    bar_lds();                                   // x_l free for next phase A; colp visible
  }
  phase_c((NTILE - 1) & 1, i0 + (NTILE - 1) * TROWS);

  // ---- publish col slice; wait for the 7 chunk-mates of this batch (device-scope release/acquire)
  __threadfence();
  __syncthreads();
  if (t == 0) {
    __hip_atomic_fetch_add(&cntA[b * 4], 1, __ATOMIC_ACQ_REL, __HIP_MEMORY_SCOPE_AGENT);
    while (__hip_atomic_load(&cntA[b * 4], __ATOMIC_ACQUIRE, __HIP_MEMORY_SCOPE_AGENT) < NCHUNK)
      __builtin_amdgcn_s_sleep(1);
  }
  __syncthreads();
  { int v = __hip_atomic_load(&cntA[b * 4], __ATOMIC_ACQUIRE, __HIP_MEMORY_SCOPE_AGENT);
    asm volatile("" :: "v"(v)); }               // per-thread acquire; keep live

  // ---- phase 2: this chunk's s-contribution = sum_k (racc + br/8)(col + bc); col is L3-hot (64 KB/b)
  const float* clp = col_ws + (size_t)b * Cdim * Kdim + 4 * t;
  #pragma unroll
  for (int c = 0; c < Cdim; ++c) {
    f32x4 cv = *(const f32x4*)(clp + (size_t)c * Kdim);
    const float brq = b_row[c] * (1.f / NCHUNK);
    const float bcv = b_col[c];
    float p = (racc[c][0] + brq) * (cv.x + bcv) + (racc[c][1] + brq) * (cv.y + bcv)
            + (racc[c][2] + brq) * (cv.z + bcv) + (racc[c][3] + brq) * (cv.w + bcv);
    #pragma unroll
    for (int off = 32; off; off >>= 1) p += __shfl_xor(p, off);
    if (lane == 0) wred[w * Cdim + c] = p;
  }
  __syncthreads();
  if (t < Cdim)
    sparts[((size_t)b * NCHUNK + ch) * Cdim + t] =
        wred[t] + wred[Cdim + t] + wred[2 * Cdim + t] + wred[3 * Cdim + t];

  // ---- publish sparts; LAST block of this batch broadcasts the output
  __threadfence();
  __syncthreads();
  if (t == 0) {
    int old = __hip_atomic_fetch_add(&cntB[b * 4], 1, __ATOMIC_ACQ_REL, __HIP_MEMORY_SCOPE_AGENT);
    lastFlag = (old == NCHUNK - 1);
  }
  __syncthreads();
  if (!lastFlag) return;

  { int v = __hip_atomic_load(&cntB[b * 4], __ATOMIC_ACQUIRE, __HIP_MEMORY_SCOPE_AGENT);
    asm volatile("" :: "v"(v)); }               // per-thread acquire before reading sparts
  if (t < Cdim) {
    float s = 0.f;
    #pragma unroll
    for (int c2 = 0; c2 < NCHUNK; ++c2) s += sparts[((size_t)b * NCHUNK + c2) * Cdim + t];
    wred[t] = s;
  }
  __syncthreads();
  float* ob = out + (size_t)b * Cdim * Kdim;
  #pragma unroll
  for (int i = t; i < Cdim * Kdim / 4; i += 256) {   // 16 f32x4 per thread
    const float s = wred[i >> 8];                    // c = i/256
    f32x4 o = {s, s, s, s};
    *(f32x4*)(ob + 4 * i) = o;
  }
}

extern "C" void kernel_launch(void* const* d_in, const int* in_sizes, int n_in,
                              void* d_out, int out_size, void* d_ws, size_t ws_size,
                              hipStream_t stream) {
  const float* x  = (const float*)d_in[0];
  const float* Wr = (const float*)d_in[1];
  const float* br = (const float*)d_in[2];
  const float* Wc = (const float*)d_in[3];
  const float* bc = (const float*)d_in[4];
  float* out = (float*)d_out;

  char* ws = (char*)d_ws;
  float* col_ws = (float*)ws;                            // 64*16*1024*4 = 4,194,304 B
  float* sparts = (float*)(ws + 4194304);                // 64*8*16*4    =    32,768 B
  int*   cntA   = (int*)  (ws + 4194304 + 32768);        // 64*4 ints    =     1,024 B
  int*   cntB   = (int*)  (ws + 4194304 + 32768 + 1024); // 64*4 ints    =     1,024 B

  hipMemsetAsync((void*)cntA, 0, 2048, stream);          // counters only; sparts/col fully overwritten
  k_fused<<<64 * NCHUNK, 256, 0, stream>>>(x, Wr, Wc, br, bc, col_ws, sparts, cntA, cntB, out);
}

// Round 7
// 160.709 us; speedup vs baseline: 1.4385x; 1.4385x over previous
//
#include <hip/hip_runtime.h>
#include <stdint.h>

typedef float  f32x4 __attribute__((ext_vector_type(4)));
typedef short  s16x8 __attribute__((ext_vector_type(8)));

constexpr int Kdim    = 1024;
constexpr int Cdim    = 16;
constexpr int NCHUNK  = 8;                 // grid = 512 -> 2 blocks/CU (LDS 74.2KB x2 <= 160KB)
constexpr int ROWS_CH = 128;               // rows per block
constexpr int TROWS   = 32;                // rows per LDS tile
constexpr int NTILE   = ROWS_CH / TROWS;   // 4
constexpr int RS      = Kdim + 8;          // bf16 row stride (2064B = 129*16B: aligned, rotates banks)

static __device__ __forceinline__ ushort f2bf(float f) {
  uint32_t u = __builtin_bit_cast(uint32_t, f);
  u += 0x7FFFu + ((u >> 16) & 1u);         // RNE
  return (ushort)(u >> 16);
}

// LDS-only barrier: ds ops drained, global prefetches stay IN FLIGHT across it.
static __device__ __forceinline__ void bar_lds() {
  __builtin_amdgcn_sched_barrier(0);
  asm volatile("s_waitcnt lgkmcnt(0)" ::: "memory");
  __builtin_amdgcn_s_barrier();
  __builtin_amdgcn_sched_barrier(0);
}

// K1 (verified round-5 structure): one read of x. r-direction on VALU; col via MFMA -> col_ws [b][c][i].
// r partials now reduced IN PLACE via fire-and-forget f32 atomics (global_atomic_add_f32):
// 4.2 MB pre-reduced buffer (L2/L3-resident) instead of a 33.6 MB bf16 round-trip. No sync, no fence.
__global__ __launch_bounds__(256, 2) void k_main(const float* __restrict__ x, const float* __restrict__ Wr,
                                                 const float* __restrict__ Wc, float* __restrict__ r_acc,
                                                 float* __restrict__ col_ws) {
  __shared__ ushort x_l[TROWS * RS];        // 66,048 B bf16 tile
  __shared__ float  colp[2][4 * 64 * 4];    //  8,192 B MFMA partials (double-buffered)

  const int t    = threadIdx.x;
  const int lane = t & 63;
  const int w    = t >> 6;
  const int b    = blockIdx.x >> 3;
  const int ch   = blockIdx.x & 7;
  const int i0   = ch * ROWS_CH;
  const float* xb = x + (size_t)b * Kdim * Kdim;
  const float* xt = xb + 4 * t;

  // ---- start the x prefetch ring FIRST (HBM latency long); depth-8: 128B/thread in flight
  f32x4 pa0, pa1, pa2, pa3, pb0, pb1, pb2, pb3;
  pa0 = *(const f32x4*)(xt + (size_t)(i0 + 0) * Kdim);
  pa1 = *(const f32x4*)(xt + (size_t)(i0 + 1) * Kdim);
  pa2 = *(const f32x4*)(xt + (size_t)(i0 + 2) * Kdim);
  pa3 = *(const f32x4*)(xt + (size_t)(i0 + 3) * Kdim);

  // ---- hoist B operand: wave w covers K-half (w>>1); build bf16 fragments from fp32 Wc (L2-hot)
  const int kh = w >> 1;
  const int kg = lane >> 4;
  const float* wcrow = Wc + (size_t)(lane & 15) * Kdim;
  s16x8 wfrag[16];
  #pragma unroll
  for (int s = 0; s < 16; ++s) {
    const float* p = wcrow + (kh * 16 + s) * 32 + kg * 8;
    f32x4 lo = *(const f32x4*)p;
    f32x4 hi = *(const f32x4*)(p + 4);
    s16x8 f;
    f[0] = (short)f2bf(lo.x); f[1] = (short)f2bf(lo.y); f[2] = (short)f2bf(lo.z); f[3] = (short)f2bf(lo.w);
    f[4] = (short)f2bf(hi.x); f[5] = (short)f2bf(hi.y); f[6] = (short)f2bf(hi.z); f[7] = (short)f2bf(hi.w);
    wfrag[s] = f;
  }

  float racc[Cdim][4];
  #pragma unroll
  for (int c = 0; c < Cdim; ++c) { racc[c][0] = racc[c][1] = racc[c][2] = racc[c][3] = 0.f; }

  auto proc_row = [&](int row, int grow, f32x4 v) {
    const float* wrp = Wr + grow;            // Wr[c][grow]: uniform -> s_load, scalar-cache resident
    #pragma unroll
    for (int c = 0; c < Cdim; ++c) {
      const float wv = wrp[(size_t)c * Kdim];
      racc[c][0] = fmaf(wv, v.x, racc[c][0]);
      racc[c][1] = fmaf(wv, v.y, racc[c][1]);
      racc[c][2] = fmaf(wv, v.z, racc[c][2]);
      racc[c][3] = fmaf(wv, v.w, racc[c][3]);
    }
    ushort4 u4 = make_ushort4(f2bf(v.x), f2bf(v.y), f2bf(v.z), f2bf(v.w));
    *(ushort4*)&x_l[row * RS + 4 * t] = u4;
  };

  auto phase_c = [&](int p, int r0p) {      // combine K-halves, store col in [b][c][i] (contig in i)
    if (t < 128) {
      const int it = t >> 6;
      const int l  = t & 63;
      f32x4 va = *(const f32x4*)&colp[p][(it * 64 + l) * 4];
      f32x4 vb = *(const f32x4*)&colp[p][((it + 2) * 64 + l) * 4];
      const int c     = l & 15;
      const int rbase = r0p + it * 16 + ((l >> 4) << 2);   // D row = (lane>>4)*4 + q
      f32x4 o = va + vb;
      *(f32x4*)(col_ws + ((size_t)(b * Cdim + c)) * Kdim + rbase) = o;
    }
  };

  for (int tl = 0; tl < NTILE; ++tl) {
    const int r0 = i0 + tl * TROWS;

    if (tl) phase_c((tl - 1) & 1, r0 - TROWS);   // prev tile's col store overlaps phase A

    // ---- phase A: stream 32 rows; pa/pb alternate; last prefetch targets next tile (survives barriers)
    for (int g = 0; g < 8; g += 2) {
      const int nr1 = r0 + (g + 1) * 4;
      pb0 = *(const f32x4*)(xt + (size_t)(nr1 + 0) * Kdim);
      pb1 = *(const f32x4*)(xt + (size_t)(nr1 + 1) * Kdim);
      pb2 = *(const f32x4*)(xt + (size_t)(nr1 + 2) * Kdim);
      pb3 = *(const f32x4*)(xt + (size_t)(nr1 + 3) * Kdim);
      proc_row(g * 4 + 0, r0 + g * 4 + 0, pa0);
      proc_row(g * 4 + 1, r0 + g * 4 + 1, pa1);
      proc_row(g * 4 + 2, r0 + g * 4 + 2, pa2);
      proc_row(g * 4 + 3, r0 + g * 4 + 3, pa3);
      const int nr2 = r0 + (g + 2) * 4;          // == r0+32 when g==6 -> next tile group 0
      if (g + 2 < 8 || tl + 1 < NTILE) {         // guards OOB read past chunk end
        pa0 = *(const f32x4*)(xt + (size_t)(nr2 + 0) * Kdim);
        pa1 = *(const f32x4*)(xt + (size_t)(nr2 + 1) * Kdim);
        pa2 = *(const f32x4*)(xt + (size_t)(nr2 + 2) * Kdim);
        pa3 = *(const f32x4*)(xt + (size_t)(nr2 + 3) * Kdim);
      }
      proc_row(g * 4 + 4, nr1 + 0, pb0);
      proc_row(g * 4 + 5, nr1 + 1, pb1);
      proc_row(g * 4 + 6, nr1 + 2, pb2);
      proc_row(g * 4 + 7, nr1 + 3, pb3);
    }
    bar_lds();                                   // x_l visible; global ring stays in flight

    // ---- phase B: col-direction MFMA. wave w: i-tile (w&1), K-half (w>>1). B operand from regs.
    {
      const int it   = w & 1;
      const int arow = it * 16 + (lane & 15);
      f32x4 acc = {0.f, 0.f, 0.f, 0.f};
      #pragma unroll
      for (int s = 0; s < 16; ++s) {
        const int ks = kh * 16 + s;
        s16x8 a = *(const s16x8*)&x_l[arow * RS + ks * 32 + kg * 8];
        acc = __builtin_amdgcn_mfma_f32_16x16x32_bf16(a, wfrag[s], acc, 0, 0, 0);
      }
      *(f32x4*)&colp[tl & 1][(w * 64 + lane) * 4] = acc;
    }
    bar_lds();                                   // x_l free for next phase A; colp visible
  }
  phase_c((NTILE - 1) & 1, i0 + (NTILE - 1) * TROWS);

  // ---- reduce r partials in place: fire-and-forget HW f32 atomics into [b][c][k] (L2/L3-resident)
  float* rp = r_acc + ((size_t)b * Cdim) * Kdim + 4 * t;
  #pragma unroll
  for (int c = 0; c < Cdim; ++c) {
    float* p = rp + (size_t)c * Kdim;
    unsafeAtomicAdd(p + 0, racc[c][0]);
    unsafeAtomicAdd(p + 1, racc[c][1]);
    unsafeAtomicAdd(p + 2, racc[c][2]);
    unsafeAtomicAdd(p + 3, racc[c][3]);
  }
}

// K2: per (b,c): s = dot(r+br, col+bc); broadcast-write 1024 outputs. All inputs L3-hot (12.6 MB).
__global__ __launch_bounds__(256) void k_out(const float* __restrict__ r_acc, const float* __restrict__ col_ws,
                                             const float* __restrict__ b_row, const float* __restrict__ b_col,
                                             float* __restrict__ out) {
  const int bid = blockIdx.x;             // 0..1023
  const int b = bid >> 4, c = bid & 15;
  const int t = threadIdx.x;
  const float br = b_row[c], bc = b_col[c];

  f32x4 rv = *(const f32x4*)(r_acc + ((size_t)(b * Cdim + c)) * Kdim + 4 * t);
  f32x4 cv = *(const f32x4*)(col_ws + ((size_t)(b * Cdim + c)) * Kdim + 4 * t);
  float part = 0.f;
  #pragma unroll
  for (int q = 0; q < 4; ++q) part += (rv[q] + br) * (cv[q] + bc);

  #pragma unroll
  for (int off = 1; off < 64; off <<= 1) part += __shfl_xor(part, off);
  __shared__ float wsum[4];
  if ((t & 63) == 0) wsum[t >> 6] = part;
  __syncthreads();
  const float s = wsum[0] + wsum[1] + wsum[2] + wsum[3];

  f32x4 o = {s, s, s, s};
  *(f32x4*)(out + ((size_t)(b * Cdim + c)) * Kdim + 4 * t) = o;
}

extern "C" void kernel_launch(void* const* d_in, const int* in_sizes, int n_in,
                              void* d_out, int out_size, void* d_ws, size_t ws_size,
                              hipStream_t stream) {
  const float* x  = (const float*)d_in[0];
  const float* Wr = (const float*)d_in[1];
  const float* br = (const float*)d_in[2];
  const float* Wc = (const float*)d_in[3];
  const float* bc = (const float*)d_in[4];
  float* out = (float*)d_out;

  char* ws = (char*)d_ws;
  float* r_acc  = (float*)ws;                    // 64*16*1024*4 = 4,194,304 B (atomic-reduced)
  float* col_ws = (float*)(ws + 4194304);        // 64*16*1024*4 = 4,194,304 B

  hipMemsetAsync((void*)r_acc, 0, 4194304, stream);   // r accumulator must start at zero
  k_main<<<512, 256, 0, stream>>>(x, Wr, Wc, r_acc, col_ws);
  k_out<<<1024, 256, 0, stream>>>(r_acc, col_ws, br, bc, out);
}

// Round 8
// 92.305 us; speedup vs baseline: 2.5045x; 1.7411x over previous
//
#include <hip/hip_runtime.h>
#include <stdint.h>

typedef float  f32x4 __attribute__((ext_vector_type(4)));
typedef short  s16x8 __attribute__((ext_vector_type(8)));

constexpr int Kdim    = 1024;
constexpr int Cdim    = 16;
constexpr int NCHUNK  = 8;                 // grid = 512 -> 2 blocks/CU (LDS 74.2KB x2 <= 160KB)
constexpr int ROWS_CH = 128;               // rows per block
constexpr int TROWS   = 32;                // rows per LDS tile
constexpr int NTILE   = ROWS_CH / TROWS;   // 4
constexpr int RS      = Kdim + 8;          // bf16 row stride (2064B = 129*16B: aligned, rotates banks)

static __device__ __forceinline__ ushort f2bf(float f) {
  uint32_t u = __builtin_bit_cast(uint32_t, f);
  u += 0x7FFFu + ((u >> 16) & 1u);         // RNE
  return (ushort)(u >> 16);
}
static __device__ __forceinline__ float bf2f(ushort u) {
  return __builtin_bit_cast(float, (uint32_t)u << 16);
}
// HW packed f32->bf16 (RNE), 1 inst per 2 values; no builtin on gfx950 -> inline asm (T12)
static __device__ __forceinline__ uint32_t cvt_pk_bf16(float a, float b) {
  uint32_t r;
  asm("v_cvt_pk_bf16_f32 %0, %1, %2" : "=v"(r) : "v"(a), "v"(b));
  return r;
}

// LDS-only barrier: ds ops drained, global prefetches stay IN FLIGHT across it.
static __device__ __forceinline__ void bar_lds() {
  __builtin_amdgcn_sched_barrier(0);
  asm volatile("s_waitcnt lgkmcnt(0)" ::: "memory");
  __builtin_amdgcn_s_barrier();
  __builtin_amdgcn_sched_barrier(0);
}

// K1 (verified round-5 structure): one read of x. r-direction on VALU (fp32 regs -> bf16 partials),
// col via MFMA -> col_ws [b][c][i]. W_col -> bf16 fragments in-register; W_row via uniform s_loads.
__global__ __launch_bounds__(256, 2) void k_main(const float* __restrict__ x, const float* __restrict__ Wr,
                                                 const float* __restrict__ Wc, ushort* __restrict__ r_bf,
                                                 float* __restrict__ col_ws) {
  __shared__ ushort x_l[TROWS * RS];        // 66,048 B bf16 tile
  __shared__ float  colp[2][4 * 64 * 4];    //  8,192 B MFMA partials (double-buffered)

  const int t    = threadIdx.x;
  const int lane = t & 63;
  const int w    = t >> 6;
  const int b    = blockIdx.x >> 3;
  const int ch   = blockIdx.x & 7;
  const int i0   = ch * ROWS_CH;
  const float* xb = x + (size_t)b * Kdim * Kdim;
  const float* xt = xb + 4 * t;

  // ---- start the x prefetch ring FIRST (HBM latency long); depth-8: 128B/thread in flight
  f32x4 pa0, pa1, pa2, pa3, pb0, pb1, pb2, pb3;
  pa0 = *(const f32x4*)(xt + (size_t)(i0 + 0) * Kdim);
  pa1 = *(const f32x4*)(xt + (size_t)(i0 + 1) * Kdim);
  pa2 = *(const f32x4*)(xt + (size_t)(i0 + 2) * Kdim);
  pa3 = *(const f32x4*)(xt + (size_t)(i0 + 3) * Kdim);

  // ---- hoist B operand: wave w covers K-half (w>>1); build bf16 fragments from fp32 Wc (L2-hot)
  const int kh = w >> 1;
  const int kg = lane >> 4;
  const float* wcrow = Wc + (size_t)(lane & 15) * Kdim;
  s16x8 wfrag[16];
  #pragma unroll
  for (int s = 0; s < 16; ++s) {
    const float* p = wcrow + (kh * 16 + s) * 32 + kg * 8;
    f32x4 lo = *(const f32x4*)p;
    f32x4 hi = *(const f32x4*)(p + 4);
    uint32_t u0 = cvt_pk_bf16(lo.x, lo.y);
    uint32_t u1 = cvt_pk_bf16(lo.z, lo.w);
    uint32_t u2 = cvt_pk_bf16(hi.x, hi.y);
    uint32_t u3 = cvt_pk_bf16(hi.z, hi.w);
    uint4 uu = {u0, u1, u2, u3};
    wfrag[s] = __builtin_bit_cast(s16x8, uu);
  }

  float racc[Cdim][4];
  #pragma unroll
  for (int c = 0; c < Cdim; ++c) { racc[c][0] = racc[c][1] = racc[c][2] = racc[c][3] = 0.f; }

  auto proc_row = [&](int row, int grow, f32x4 v) {
    const float* wrp = Wr + grow;            // Wr[c][grow]: uniform -> s_load, scalar-cache resident
    #pragma unroll
    for (int c = 0; c < Cdim; ++c) {
      const float wv = wrp[(size_t)c * Kdim];
      racc[c][0] = fmaf(wv, v.x, racc[c][0]);
      racc[c][1] = fmaf(wv, v.y, racc[c][1]);
      racc[c][2] = fmaf(wv, v.z, racc[c][2]);
      racc[c][3] = fmaf(wv, v.w, racc[c][3]);
    }
    uint2 u = {cvt_pk_bf16(v.x, v.y), cvt_pk_bf16(v.z, v.w)};   // 2 inst vs 16
    *(uint2*)&x_l[row * RS + 4 * t] = u;
  };

  auto phase_c = [&](int p, int r0p) {      // combine K-halves, store col in [b][c][i] (contig in i)
    if (t < 128) {
      const int it = t >> 6;
      const int l  = t & 63;
      f32x4 va = *(const f32x4*)&colp[p][(it * 64 + l) * 4];
      f32x4 vb = *(const f32x4*)&colp[p][((it + 2) * 64 + l) * 4];
      const int c     = l & 15;
      const int rbase = r0p + it * 16 + ((l >> 4) << 2);   // D row = (lane>>4)*4 + q
      f32x4 o = va + vb;
      *(f32x4*)(col_ws + ((size_t)(b * Cdim + c)) * Kdim + rbase) = o;
    }
  };

  for (int tl = 0; tl < NTILE; ++tl) {
    const int r0 = i0 + tl * TROWS;

    if (tl) phase_c((tl - 1) & 1, r0 - TROWS);   // prev tile's col store overlaps phase A

    // ---- phase A: stream 32 rows; pa/pb alternate; last prefetch targets next tile (survives barriers)
    for (int g = 0; g < 8; g += 2) {
      const int nr1 = r0 + (g + 1) * 4;
      pb0 = *(const f32x4*)(xt + (size_t)(nr1 + 0) * Kdim);
      pb1 = *(const f32x4*)(xt + (size_t)(nr1 + 1) * Kdim);
      pb2 = *(const f32x4*)(xt + (size_t)(nr1 + 2) * Kdim);
      pb3 = *(const f32x4*)(xt + (size_t)(nr1 + 3) * Kdim);
      proc_row(g * 4 + 0, r0 + g * 4 + 0, pa0);
      proc_row(g * 4 + 1, r0 + g * 4 + 1, pa1);
      proc_row(g * 4 + 2, r0 + g * 4 + 2, pa2);
      proc_row(g * 4 + 3, r0 + g * 4 + 3, pa3);
      const int nr2 = r0 + (g + 2) * 4;          // == r0+32 when g==6 -> next tile group 0
      if (g + 2 < 8 || tl + 1 < NTILE) {         // guards OOB read past chunk end
        pa0 = *(const f32x4*)(xt + (size_t)(nr2 + 0) * Kdim);
        pa1 = *(const f32x4*)(xt + (size_t)(nr2 + 1) * Kdim);
        pa2 = *(const f32x4*)(xt + (size_t)(nr2 + 2) * Kdim);
        pa3 = *(const f32x4*)(xt + (size_t)(nr2 + 3) * Kdim);
      }
      proc_row(g * 4 + 4, nr1 + 0, pb0);
      proc_row(g * 4 + 5, nr1 + 1, pb1);
      proc_row(g * 4 + 6, nr1 + 2, pb2);
      proc_row(g * 4 + 7, nr1 + 3, pb3);
    }
    bar_lds();                                   // x_l visible; global ring stays in flight

    // ---- phase B: col-direction MFMA. wave w: i-tile (w&1), K-half (w>>1). B operand from regs.
    {
      const int it   = w & 1;
      const int arow = it * 16 + (lane & 15);
      f32x4 acc = {0.f, 0.f, 0.f, 0.f};
      #pragma unroll
      for (int s = 0; s < 16; ++s) {
        const int ks = kh * 16 + s;
        s16x8 a = *(const s16x8*)&x_l[arow * RS + ks * 32 + kg * 8];
        acc = __builtin_amdgcn_mfma_f32_16x16x32_bf16(a, wfrag[s], acc, 0, 0, 0);
      }
      *(f32x4*)&colp[tl & 1][(w * 64 + lane) * 4] = acc;
    }
    bar_lds();                                   // x_l free for next phase A; colp visible
  }
  phase_c((NTILE - 1) & 1, i0 + (NTILE - 1) * TROWS);

  // ---- write r partials for this chunk as bf16: [b][ch][c][k], coalesced 8B stores
  ushort* rp = r_bf + ((size_t)(b * NCHUNK + ch) * Cdim) * Kdim + 4 * t;
  #pragma unroll
  for (int c = 0; c < Cdim; ++c) {
    uint2 u = {cvt_pk_bf16(racc[c][0], racc[c][1]), cvt_pk_bf16(racc[c][2], racc[c][3])};
    *(uint2*)(rp + (size_t)c * Kdim) = u;
  }
}

// K2 (fused): per (b,c): r = sum of bf16 chunk partials; s = dot(r+br, col+bc); broadcast-write 1024 outputs
__global__ __launch_bounds__(256) void k_out(const ushort* __restrict__ r_bf, const float* __restrict__ col_ws,
                                             const float* __restrict__ b_row, const float* __restrict__ b_col,
                                             float* __restrict__ out) {
  const int bid = blockIdx.x;             // 0..1023
  const int b = bid >> 4, c = bid & 15;
  const int t = threadIdx.x;
  const float br = b_row[c], bc = b_col[c];

  f32x4 rv = {0.f, 0.f, 0.f, 0.f};
  #pragma unroll
  for (int ch = 0; ch < NCHUNK; ++ch) {
    ushort4 u = *(const ushort4*)(r_bf + ((size_t)(b * NCHUNK + ch) * Cdim + c) * Kdim + 4 * t);
    rv.x += bf2f(u.x); rv.y += bf2f(u.y); rv.z += bf2f(u.z); rv.w += bf2f(u.w);
  }
  f32x4 cv = *(const f32x4*)(col_ws + ((size_t)(b * Cdim + c)) * Kdim + 4 * t);
  float part = 0.f;
  #pragma unroll
  for (int q = 0; q < 4; ++q) part += (rv[q] + br) * (cv[q] + bc);

  #pragma unroll
  for (int off = 1; off < 64; off <<= 1) part += __shfl_xor(part, off);
  __shared__ float wsum[4];
  if ((t & 63) == 0) wsum[t >> 6] = part;
  __syncthreads();
  const float s = wsum[0] + wsum[1] + wsum[2] + wsum[3];

  f32x4 o = {s, s, s, s};
  *(f32x4*)(out + ((size_t)(b * Cdim + c)) * Kdim + 4 * t) = o;
}

extern "C" void kernel_launch(void* const* d_in, const int* in_sizes, int n_in,
                              void* d_out, int out_size, void* d_ws, size_t ws_size,
                              hipStream_t stream) {
  const float* x  = (const float*)d_in[0];
  const float* Wr = (const float*)d_in[1];
  const float* br = (const float*)d_in[2];
  const float* Wc = (const float*)d_in[3];
  const float* bc = (const float*)d_in[4];
  float* out = (float*)d_out;

  char* ws = (char*)d_ws;
  ushort* r_bf   = (ushort*)ws;                  // 64*8*16*1024*2 = 16,777,216 B
  float*  col_ws = (float*)(ws + 16777216);      // 64*16*1024*4   =  4,194,304 B

  k_main<<<512, 256, 0, stream>>>(x, Wr, Wc, r_bf, col_ws);
  k_out<<<1024, 256, 0, stream>>>(r_bf, col_ws, br, bc, out);
}

// Round 9
// 60.197 us; speedup vs baseline: 3.8403x; 1.5334x over previous
//
#include <hip/hip_runtime.h>
#include <stdint.h>

typedef float  f32x4 __attribute__((ext_vector_type(4)));
typedef short  s16x8 __attribute__((ext_vector_type(8)));

constexpr int Kdim    = 1024;
constexpr int Cdim    = 16;
constexpr int NCHUNK  = 8;                 // grid = 512 -> 2 blocks/CU (LDS 74.2KB x2 <= 160KB)
constexpr int ROWS_CH = 128;               // rows per block
constexpr int TROWS   = 32;                // rows per LDS tile
constexpr int NTILE   = ROWS_CH / TROWS;   // 4
constexpr int RS      = Kdim + 8;          // bf16 row stride (2064B = 129*16B: aligned, rotates banks)

static __device__ __forceinline__ ushort f2bf(float f) {
  uint32_t u = __builtin_bit_cast(uint32_t, f);
  u += 0x7FFFu + ((u >> 16) & 1u);         // RNE
  return (ushort)(u >> 16);
}
static __device__ __forceinline__ float bf2f(ushort u) {
  return __builtin_bit_cast(float, (uint32_t)u << 16);
}

// LDS-only barrier: ds ops drained, global prefetches stay IN FLIGHT across it.
static __device__ __forceinline__ void bar_lds() {
  __builtin_amdgcn_sched_barrier(0);
  asm volatile("s_waitcnt lgkmcnt(0)" ::: "memory");
  __builtin_amdgcn_s_barrier();
  __builtin_amdgcn_sched_barrier(0);
}

// K1: one read of x. r-direction on VALU (fp32 regs -> bf16 partials), col via MFMA -> col_ws [b][c][i].
// W_col converted to bf16 fragments in-register (L2-hot fp32 reads); W_row read via uniform s_loads.
// NOTE: f2bf stays integer-ALU (schedulable); inline-asm v_cvt_pk_bf16_f32 measured -53% here (r8/m240).
__global__ __launch_bounds__(256, 2) void k_main(const float* __restrict__ x, const float* __restrict__ Wr,
                                                 const float* __restrict__ Wc, ushort* __restrict__ r_bf,
                                                 float* __restrict__ col_ws) {
  __shared__ ushort x_l[TROWS * RS];        // 66,048 B bf16 tile
  __shared__ float  colp[2][4 * 64 * 4];    //  8,192 B MFMA partials (double-buffered)

  const int t    = threadIdx.x;
  const int lane = t & 63;
  const int w    = t >> 6;
  const int b    = blockIdx.x >> 3;
  const int ch   = blockIdx.x & 7;
  const int i0   = ch * ROWS_CH;
  const float* xb = x + (size_t)b * Kdim * Kdim;
  const float* xt = xb + 4 * t;

  // ---- start the x prefetch ring FIRST (HBM latency long); depth-8: 128B/thread in flight
  f32x4 pa0, pa1, pa2, pa3, pb0, pb1, pb2, pb3;
  pa0 = *(const f32x4*)(xt + (size_t)(i0 + 0) * Kdim);
  pa1 = *(const f32x4*)(xt + (size_t)(i0 + 1) * Kdim);
  pa2 = *(const f32x4*)(xt + (size_t)(i0 + 2) * Kdim);
  pa3 = *(const f32x4*)(xt + (size_t)(i0 + 3) * Kdim);

  // ---- hoist B operand: wave w covers K-half (w>>1); build bf16 fragments from fp32 Wc (L2-hot)
  const int kh = w >> 1;
  const int kg = lane >> 4;
  const float* wcrow = Wc + (size_t)(lane & 15) * Kdim;
  s16x8 wfrag[16];
  #pragma unroll
  for (int s = 0; s < 16; ++s) {
    const float* p = wcrow + (kh * 16 + s) * 32 + kg * 8;
    f32x4 lo = *(const f32x4*)p;
    f32x4 hi = *(const f32x4*)(p + 4);
    s16x8 f;
    f[0] = (short)f2bf(lo.x); f[1] = (short)f2bf(lo.y); f[2] = (short)f2bf(lo.z); f[3] = (short)f2bf(lo.w);
    f[4] = (short)f2bf(hi.x); f[5] = (short)f2bf(hi.y); f[6] = (short)f2bf(hi.z); f[7] = (short)f2bf(hi.w);
    wfrag[s] = f;
  }

  float racc[Cdim][4];
  #pragma unroll
  for (int c = 0; c < Cdim; ++c) { racc[c][0] = racc[c][1] = racc[c][2] = racc[c][3] = 0.f; }

  auto proc_row = [&](int row, int grow, f32x4 v) {
    const float* wrp = Wr + grow;            // Wr[c][grow]: uniform -> s_load, scalar-cache resident
    #pragma unroll
    for (int c = 0; c < Cdim; ++c) {
      const float wv = wrp[(size_t)c * Kdim];
      racc[c][0] = fmaf(wv, v.x, racc[c][0]);
      racc[c][1] = fmaf(wv, v.y, racc[c][1]);
      racc[c][2] = fmaf(wv, v.z, racc[c][2]);
      racc[c][3] = fmaf(wv, v.w, racc[c][3]);
    }
    ushort4 u4 = make_ushort4(f2bf(v.x), f2bf(v.y), f2bf(v.z), f2bf(v.w));
    *(ushort4*)&x_l[row * RS + 4 * t] = u4;
  };

  auto phase_c = [&](int p, int r0p) {      // combine K-halves, store col in [b][c][i] (contig in i)
    if (t < 128) {
      const int it = t >> 6;
      const int l  = t & 63;
      f32x4 va = *(const f32x4*)&colp[p][(it * 64 + l) * 4];
      f32x4 vb = *(const f32x4*)&colp[p][((it + 2) * 64 + l) * 4];
      const int c     = l & 15;
      const int rbase = r0p + it * 16 + ((l >> 4) << 2);   // D row = (lane>>4)*4 + q
      f32x4 o = va + vb;
      *(f32x4*)(col_ws + ((size_t)(b * Cdim + c)) * Kdim + rbase) = o;
    }
  };

  for (int tl = 0; tl < NTILE; ++tl) {
    const int r0 = i0 + tl * TROWS;

    if (tl) phase_c((tl - 1) & 1, r0 - TROWS);   // prev tile's col store overlaps phase A

    // ---- phase A: stream 32 rows; pa/pb alternate; last prefetch targets next tile (survives barriers)
    for (int g = 0; g < 8; g += 2) {
      const int nr1 = r0 + (g + 1) * 4;
      pb0 = *(const f32x4*)(xt + (size_t)(nr1 + 0) * Kdim);
      pb1 = *(const f32x4*)(xt + (size_t)(nr1 + 1) * Kdim);
      pb2 = *(const f32x4*)(xt + (size_t)(nr1 + 2) * Kdim);
      pb3 = *(const f32x4*)(xt + (size_t)(nr1 + 3) * Kdim);
      proc_row(g * 4 + 0, r0 + g * 4 + 0, pa0);
      proc_row(g * 4 + 1, r0 + g * 4 + 1, pa1);
      proc_row(g * 4 + 2, r0 + g * 4 + 2, pa2);
      proc_row(g * 4 + 3, r0 + g * 4 + 3, pa3);
      const int nr2 = r0 + (g + 2) * 4;          // == r0+32 when g==6 -> next tile group 0
      if (g + 2 < 8 || tl + 1 < NTILE) {         // guards OOB read past chunk end
        pa0 = *(const f32x4*)(xt + (size_t)(nr2 + 0) * Kdim);
        pa1 = *(const f32x4*)(xt + (size_t)(nr2 + 1) * Kdim);
        pa2 = *(const f32x4*)(xt + (size_t)(nr2 + 2) * Kdim);
        pa3 = *(const f32x4*)(xt + (size_t)(nr2 + 3) * Kdim);
      }
      proc_row(g * 4 + 4, nr1 + 0, pb0);
      proc_row(g * 4 + 5, nr1 + 1, pb1);
      proc_row(g * 4 + 6, nr1 + 2, pb2);
      proc_row(g * 4 + 7, nr1 + 3, pb3);
    }
    bar_lds();                                   // x_l visible; global ring stays in flight

    // ---- phase B: col-direction MFMA. wave w: i-tile (w&1), K-half (w>>1). B operand from regs.
    {
      const int it   = w & 1;
      const int arow = it * 16 + (lane & 15);
      f32x4 acc = {0.f, 0.f, 0.f, 0.f};
      #pragma unroll
      for (int s = 0; s < 16; ++s) {
        const int ks = kh * 16 + s;
        s16x8 a = *(const s16x8*)&x_l[arow * RS + ks * 32 + kg * 8];
        acc = __builtin_amdgcn_mfma_f32_16x16x32_bf16(a, wfrag[s], acc, 0, 0, 0);
      }
      *(f32x4*)&colp[tl & 1][(w * 64 + lane) * 4] = acc;
    }
    bar_lds();                                   // x_l free for next phase A; colp visible
  }
  phase_c((NTILE - 1) & 1, i0 + (NTILE - 1) * TROWS);

  // ---- write r partials for this chunk as bf16: [b][ch][c][k], coalesced 8B stores
  ushort* rp = r_bf + ((size_t)(b * NCHUNK + ch) * Cdim) * Kdim + 4 * t;
  #pragma unroll
  for (int c = 0; c < Cdim; ++c) {
    ushort4 u4 = make_ushort4(f2bf(racc[c][0]), f2bf(racc[c][1]), f2bf(racc[c][2]), f2bf(racc[c][3]));
    *(ushort4*)(rp + (size_t)c * Kdim) = u4;
  }
}

// K2 (fused): per (b,c): r = sum of bf16 chunk partials; s = dot(r+br, col+bc); broadcast-write 1024 outputs
__global__ __launch_bounds__(256) void k_out(const ushort* __restrict__ r_bf, const float* __restrict__ col_ws,
                                             const float* __restrict__ b_row, const float* __restrict__ b_col,
                                             float* __restrict__ out) {
  const int bid = blockIdx.x;             // 0..1023
  const int b = bid >> 4, c = bid & 15;
  const int t = threadIdx.x;
  const float br = b_row[c], bc = b_col[c];

  f32x4 rv = {0.f, 0.f, 0.f, 0.f};
  #pragma unroll
  for (int ch = 0; ch < NCHUNK; ++ch) {
    ushort4 u = *(const ushort4*)(r_bf + ((size_t)(b * NCHUNK + ch) * Cdim + c) * Kdim + 4 * t);
    rv.x += bf2f(u.x); rv.y += bf2f(u.y); rv.z += bf2f(u.z); rv.w += bf2f(u.w);
  }
  f32x4 cv = *(const f32x4*)(col_ws + ((size_t)(b * Cdim + c)) * Kdim + 4 * t);
  float part = 0.f;
  #pragma unroll
  for (int q = 0; q < 4; ++q) part += (rv[q] + br) * (cv[q] + bc);

  #pragma unroll
  for (int off = 1; off < 64; off <<= 1) part += __shfl_xor(part, off);
  __shared__ float wsum[4];
  if ((t & 63) == 0) wsum[t >> 6] = part;
  __syncthreads();
  const float s = wsum[0] + wsum[1] + wsum[2] + wsum[3];

  f32x4 o = {s, s, s, s};
  *(f32x4*)(out + ((size_t)(b * Cdim + c)) * Kdim + 4 * t) = o;
}

extern "C" void kernel_launch(void* const* d_in, const int* in_sizes, int n_in,
                              void* d_out, int out_size, void* d_ws, size_t ws_size,
                              hipStream_t stream) {
  const float* x  = (const float*)d_in[0];
  const float* Wr = (const float*)d_in[1];
  const float* br = (const float*)d_in[2];
  const float* Wc = (const float*)d_in[3];
  const float* bc = (const float*)d_in[4];
  float* out = (float*)d_out;

  char* ws = (char*)d_ws;
  ushort* r_bf   = (ushort*)ws;                  // 64*8*16*1024*2 = 16,777,216 B
  float*  col_ws = (float*)(ws + 16777216);      // 64*16*1024*4   =  4,194,304 B

  k_main<<<512, 256, 0, stream>>>(x, Wr, Wc, r_bf, col_ws);
  k_out<<<1024, 256, 0, stream>>>(r_bf, col_ws, br, bc, out);
}